// Round 13
// baseline (170.134 us; speedup 1.0000x reference)
//
#include <hip/hip_runtime.h>
#include <math.h>

#define S 2048
#define E 1024
#define D 64
#define H 16

using f16 = _Float16;
typedef _Float16 v8h __attribute__((ext_vector_type(8)));  // 8 fp16 (4 VGPRs)
typedef _Float16 v4h __attribute__((ext_vector_type(4)));
typedef float v4f __attribute__((ext_vector_type(4)));

#define QSCALE (0.125f * 1.44269504f)   // 1/sqrt(D) * log2(e), folded into Q

__device__ __forceinline__ float fexp2(float x) { return __builtin_amdgcn_exp2f(x); }

// async global->LDS, 16 B per lane; LDS dest = wave-uniform base + lane*16
__device__ __forceinline__ void glds16(const f16* g, f16* l) {
    __builtin_amdgcn_global_load_lds(
        (const __attribute__((address_space(1))) void*)g,
        (__attribute__((address_space(3))) void*)l, 16, 0, 0);
}

// ---------------------------------------------------------------------------
// Kernel 0: fused prep. blocks [0,3072): x/Wo fp32->fp16 converts.
// blocks [3072, 3840): folded weights Wc[type,h] = hW[type,h] @ W[type].
// ---------------------------------------------------------------------------
__global__ void prep(const float* __restrict__ x, const float* __restrict__ Wo,
                     const float* __restrict__ hWk, const float* __restrict__ hWq,
                     const float* __restrict__ hWv,
                     const float* __restrict__ Wk, const float* __restrict__ Wq,
                     const float* __restrict__ Wv,
                     f16* __restrict__ Xh, f16* __restrict__ WoB,
                     f16* __restrict__ Wc) {
    __shared__ f16 Ah[64][72];
    __shared__ f16 Bt[64][72];
    const int t = threadIdx.x;

    if (blockIdx.x < 3072) {             // converts
        const size_t i = (size_t)blockIdx.x * 256 + t;
        const size_t NX = (size_t)S * E / 4;
        if (i < NX) {
            v4f w = ((const v4f*)x)[i];
            v4h h = {(f16)w[0], (f16)w[1], (f16)w[2], (f16)w[3]};
            ((v4h*)Xh)[i] = h;
        } else {
            const size_t j = i - NX;
            v4f w = ((const v4f*)Wo)[j];
            v4h h = {(f16)w[0], (f16)w[1], (f16)w[2], (f16)w[3]};
            ((v4h*)WoB)[j] = h;
        }
        return;
    }

    const int bb = blockIdx.x - 3072;    // 0..767
    const int th = bb >> 4;              // 0..47
    const int type = th >> 4, h = th & 15;
    const int e0 = (bb & 15) * 64;
    const float* hW = ((type == 0) ? hWk : (type == 1) ? hWq : hWv) + (size_t)h * D * D;
    const float* W  = (type == 0) ? Wk : (type == 1) ? Wq : Wv;

    {
        const int r16 = t >> 4, c4 = (t & 15) * 4;
#pragma unroll
        for (int rep = 0; rep < 4; ++rep) {
            const int row = rep * 16 + r16;
            v4f a = *(const v4f*)&hW[(size_t)row * D + c4];
#pragma unroll
            for (int j = 0; j < 4; ++j) Ah[row][c4 + j] = (f16)a[j];
            v4f w = *(const v4f*)&W[(size_t)row * E + e0 + c4];
#pragma unroll
            for (int j = 0; j < 4; ++j) Bt[c4 + j][row] = (f16)w[j];
        }
    }
    __syncthreads();

    const int wave = t >> 6, lane = t & 63;
    const int quad = lane >> 4, l16 = lane & 15;
    v4f acc[4] = {};
#pragma unroll
    for (int ks = 0; ks < 2; ++ks) {
        v8h af = *(const v8h*)&Ah[wave * 16 + l16][ks * 32 + quad * 8];
#pragma unroll
        for (int nt = 0; nt < 4; ++nt) {
            v8h bf = *(const v8h*)&Bt[nt * 16 + l16][ks * 32 + quad * 8];
            acc[nt] = __builtin_amdgcn_mfma_f32_16x16x32_f16(af, bf, acc[nt], 0, 0, 0);
        }
    }
#pragma unroll
    for (int r = 0; r < 4; ++r) {
        const int e2 = wave * 16 + quad * 4 + r;
#pragma unroll
        for (int nt = 0; nt < 4; ++nt)
            Wc[((size_t)th * D + e2) * E + e0 + nt * 16 + l16] = (f16)acc[nt][r];
    }
}

// ---------------------------------------------------------------------------
// Kernel 1: QKV GEMM (m97 recipe). K written [h][s][d]; Q written [h][s][d]
// PRE-SCALED by QSCALE (softmax scale folded in); V written TRANSPOSED to
// VhT [h][d][s]. grid (S/128, 3072/64), block 256.
// ---------------------------------------------------------------------------
__global__ __launch_bounds__(256) void qkv_gemm(
        const f16* __restrict__ Xh, const f16* __restrict__ Wc,
        const float* __restrict__ hbk, const float* __restrict__ hbq,
        const float* __restrict__ hbv,
        f16* __restrict__ Kh, f16* __restrict__ Qh, f16* __restrict__ VhT) {
    const int m0 = blockIdx.x * 128;
    const int n0 = blockIdx.y * 64;
    const int type = n0 >> 10, h = (n0 >> 6) & 15;
    const float* hb = ((type == 0) ? hbk : (type == 1) ? hbq : hbv) + h * D;

    const int t = threadIdx.x;
    const int wave = t >> 6, lane = t & 63;
    const int quad = lane >> 4, l16 = lane & 15;
    const int wm = wave >> 1, wn = wave & 1;

    __shared__ f16 As[128 * 64];
    __shared__ f16 Bs[64 * 64];

    v4f acc[4][2] = {};
    const int lrow8 = lane >> 3, lg = lane & 7;

    for (int k0 = 0; k0 < E; k0 += 64) {
        __syncthreads();
#pragma unroll
        for (int jj = 0; jj < 4; ++jj) {
            const int j = wave * 4 + jj;
            const int row = j * 8 + lrow8;
            const int g = lg ^ (row & 7);
            glds16(Xh + (size_t)(m0 + row) * E + k0 + g * 8, &As[j * 512]);
        }
#pragma unroll
        for (int jj = 0; jj < 2; ++jj) {
            const int j = wave * 2 + jj;
            const int row = j * 8 + lrow8;
            const int g = lg ^ (row & 7);
            glds16(Wc + (size_t)(n0 + row) * E + k0 + g * 8, &Bs[j * 512]);
        }
        __syncthreads();

#pragma unroll
        for (int ks = 0; ks < 2; ++ks) {
            v8h a[4], b[2];
#pragma unroll
            for (int mt = 0; mt < 4; ++mt) {
                const int row = wm * 64 + mt * 16 + l16;
                a[mt] = *(const v8h*)&As[row * 64 + (((ks * 4 + quad) ^ (row & 7)) * 8)];
            }
#pragma unroll
            for (int nt = 0; nt < 2; ++nt) {
                const int row = wn * 32 + nt * 16 + l16;
                b[nt] = *(const v8h*)&Bs[row * 64 + (((ks * 4 + quad) ^ (row & 7)) * 8)];
            }
#pragma unroll
            for (int mt = 0; mt < 4; ++mt)
#pragma unroll
                for (int nt = 0; nt < 2; ++nt)
                    acc[mt][nt] = __builtin_amdgcn_mfma_f32_16x16x32_f16(a[mt], b[nt], acc[mt][nt], 0, 0, 0);
        }
    }

    if (type == 2) {                     // V: write transposed [h][d][s]
#pragma unroll
        for (int mt = 0; mt < 4; ++mt)
#pragma unroll
            for (int nt = 0; nt < 2; ++nt) {
                const int d = wn * 32 + nt * 16 + l16;
                const int s = m0 + wm * 64 + mt * 16 + quad * 4;
                const float b = hb[d];
                v4h vh;
#pragma unroll
                for (int r = 0; r < 4; ++r) vh[r] = (f16)(acc[mt][nt][r] + b);
                *(v4h*)(VhT + ((size_t)h * D + d) * S + s) = vh;
            }
    } else {
        f16* outp = (type == 0) ? Kh : Qh;
        const float osc = (type == 1) ? QSCALE : 1.f;
#pragma unroll
        for (int mt = 0; mt < 4; ++mt)
#pragma unroll
            for (int r = 0; r < 4; ++r) {
                const int s = m0 + wm * 64 + mt * 16 + quad * 4 + r;
#pragma unroll
                for (int nt = 0; nt < 2; ++nt) {
                    const int d = wn * 32 + nt * 16 + l16;
                    outp[((size_t)h * S + s) * D + d] = (f16)((acc[mt][nt][r] + hb[d]) * osc);
                }
            }
    }
}

// ---------------------------------------------------------------------------
// Kernel 2: MFMA flash attention (online softmax, log2-domain scores since
// QSCALE is folded into Q). Transposed scores K@Q^T; glds16 staging; ones-tile
// l; TREE max (r13: serial 16-deep fmax chain was the latency wall).
// grid = (S/64, H, 4), block = 256.
// NOTE (r11): per-row max is load-bearing — log2-score row-max ~43, no fixed
// shift fits fp16.
// ---------------------------------------------------------------------------
#define NSPLIT 4
#define KSPAN (S / NSPLIT)      // 512
#define ITERS (KSPAN / 64)      // 8
#define PPAD 72

__global__ __launch_bounds__(256, 5) void attn_mfma(
        const f16* __restrict__ Qh, const f16* __restrict__ Kh,
        const f16* __restrict__ VhT, f16* __restrict__ Opart,
        float* __restrict__ ml) {
    const int h = blockIdx.y;
    const int q0 = blockIdx.x * 64;
    const int sp = blockIdx.z;
    const int t = threadIdx.x;
    const int wave = t >> 6, lane = t & 63;
    const int quad = lane >> 4, l16 = lane & 15;

    __shared__ f16 Kt[64 * 64];          // [key][d], swizzled granules
    __shared__ f16 Vt[80 * 64];          // [d][key] rows 0-63; rows 64-79 = 1.0
    __shared__ union { f16 P[4][16][PPAD]; f16 O[64][PPAD]; } PO;

    {
        v4h one = {(f16)1, (f16)1, (f16)1, (f16)1};
        *(v4h*)&Vt[64 * 64 + t * 4] = one;
    }

    const int qrow = q0 + wave * 16 + l16;
    v8h qf[2];
    {
        const v8h* qp = (const v8h*)(Qh + ((size_t)h * S + qrow) * D);
        qf[0] = qp[quad];
        qf[1] = qp[quad + 4];
    }

    v4f oc[5] = {};                      // [0..3]=O^T d-tiles, [4]=l (ones)
    float m_run = -INFINITY;
    const int kb = sp * KSPAN;
    const int srow = lane >> 3, sg = lane & 7;

    for (int it = 0; it < ITERS; ++it) {
        __syncthreads();                 // prev compute done reading Kt/Vt
#pragma unroll
        for (int half = 0; half < 2; ++half) {
            const int row = wave * 16 + half * 8 + srow;
            const int g = sg ^ (row & 7);
            glds16(Kh + ((size_t)h * S + kb + it * 64 + row) * D + g * 8,
                   &Kt[(wave * 16 + half * 8) * 64]);
            glds16(VhT + ((size_t)h * D + row) * S + kb + it * 64 + g * 8,
                   &Vt[(wave * 16 + half * 8) * 64]);
        }
        __syncthreads();                 // DMA drained

        // scores^T (log2-domain): C[key][q], A = K rows, B = Q frag
        v4f sc[4] = {};
#pragma unroll
        for (int ks = 0; ks < 2; ++ks)
#pragma unroll
            for (int mt = 0; mt < 4; ++mt) {
                const int key = mt * 16 + l16;
                v8h kf = *(const v8h*)&Kt[key * 64 + (((ks * 4 + quad) ^ (key & 7)) * 8)];
                sc[mt] = __builtin_amdgcn_mfma_f32_16x16x32_f16(kf, qf[ks], sc[mt], 0, 0, 0);
            }

        // tree max over 16 in-register scores (depth 4, max3-foldable)
        float a0 = fmaxf(sc[0][0], sc[0][1]), a1 = fmaxf(sc[0][2], sc[0][3]);
        float a2 = fmaxf(sc[1][0], sc[1][1]), a3 = fmaxf(sc[1][2], sc[1][3]);
        float a4 = fmaxf(sc[2][0], sc[2][1]), a5 = fmaxf(sc[2][2], sc[2][3]);
        float a6 = fmaxf(sc[3][0], sc[3][1]), a7 = fmaxf(sc[3][2], sc[3][3]);
        float b0 = fmaxf(a0, a1), b1 = fmaxf(a2, a3);
        float b2 = fmaxf(a4, a5), b3 = fmaxf(a6, a7);
        float v = fmaxf(fmaxf(b0, b1), fmaxf(b2, b3));
        v = fmaxf(v, __shfl_xor(v, 16));
        v = fmaxf(v, __shfl_xor(v, 32));
        const float mnew = fmaxf(m_run, v);
        const float alpha = fexp2(m_run - mnew);   // first iter: exp2(-inf)=0
        m_run = mnew;
#pragma unroll
        for (int i = 0; i < 5; ++i) oc[i] *= alpha;

#pragma unroll
        for (int mt = 0; mt < 4; ++mt) {
            const float p0 = fexp2(sc[mt][0] - mnew);
            const float p1 = fexp2(sc[mt][1] - mnew);
            const float p2 = fexp2(sc[mt][2] - mnew);
            const float p3 = fexp2(sc[mt][3] - mnew);
            auto lo = __builtin_amdgcn_cvt_pkrtz(p0, p1);
            auto hi = __builtin_amdgcn_cvt_pkrtz(p2, p3);
            v4h ph; ph[0] = lo[0]; ph[1] = lo[1]; ph[2] = hi[0]; ph[3] = hi[1];
            *(v4h*)&PO.P[wave][l16][mt * 16 + quad * 4] = ph;   // P^T [q][key]
        }
        // Pt is wave-private: in-wave DS ordering suffices (no barrier).

        // PV: O^T += V^T @ P^T (+ ones tile accumulates l)
#pragma unroll
        for (int ks = 0; ks < 2; ++ks) {
            v8h pf = *(const v8h*)&PO.P[wave][l16][ks * 32 + quad * 8];
#pragma unroll
            for (int mt = 0; mt < 5; ++mt) {
                const int dr = mt * 16 + l16;
                v8h vf = *(const v8h*)&Vt[dr * 64 + (((ks * 4 + quad) ^ (dr & 7)) * 8)];
                oc[mt] = __builtin_amdgcn_mfma_f32_16x16x32_f16(vf, pf, oc[mt], 0, 0, 0);
            }
        }
    }

    // epilogue: l from ones tile; normalize; transpose O^T->O via LDS (union)
    const float l = oc[4][0];
    const float invl = 1.f / l;
    __syncthreads();                     // all waves done with PO.P
#pragma unroll
    for (int mt = 0; mt < 4; ++mt) {
        auto lo = __builtin_amdgcn_cvt_pkrtz(oc[mt][0] * invl, oc[mt][1] * invl);
        auto hi = __builtin_amdgcn_cvt_pkrtz(oc[mt][2] * invl, oc[mt][3] * invl);
        v4h oh; oh[0] = lo[0]; oh[1] = lo[1]; oh[2] = hi[0]; oh[3] = hi[1];
        *(v4h*)&PO.O[wave * 16 + l16][mt * 16 + quad * 4] = oh;
    }
    if (quad == 0) {
        float* mlp = ml + (((size_t)sp * H + h) * S + qrow) * 2;
        mlp[0] = m_run;
        mlp[1] = l;
    }
    __syncthreads();
    {
        const int q = t >> 2, dg = (t & 3) * 16;
        v8h o0 = *(const v8h*)&PO.O[q][dg];
        v8h o1 = *(const v8h*)&PO.O[q][dg + 8];
        f16* dst = Opart + (((size_t)sp * H + h) * S + q0 + q) * D + dg;
        *(v8h*)dst = o0;
        *(v8h*)(dst + 8) = o1;
    }
}

// ---------------------------------------------------------------------------
// Kernel 2b: combine 4 splits (m-aware), vectorized v4h. grid = S, block 256.
// Thread t owns d-range [t*4 & 63 .. +3] of head (t*4)>>6.
// ---------------------------------------------------------------------------
__global__ void attn_combine(const f16* __restrict__ Opart,
                             const float* __restrict__ ml,
                             f16* __restrict__ cat) {
    const int q = blockIdx.x;
    const int t = threadIdx.x;
    const int idx = t * 4;                // 0..1020
    const int h = idx >> 6, d0 = idx & 63;

    float m[NSPLIT], lv[NSPLIT];
    float M = -INFINITY;
#pragma unroll
    for (int sp = 0; sp < NSPLIT; ++sp) {
        const float* mlp = ml + (((size_t)sp * H + h) * S + q) * 2;
        m[sp] = mlp[0]; lv[sp] = mlp[1];
        M = fmaxf(M, m[sp]);
    }
    float asum = 0.f;
    float o[4] = {0.f, 0.f, 0.f, 0.f};
#pragma unroll
    for (int sp = 0; sp < NSPLIT; ++sp) {
        const float a = fexp2(m[sp] - M) * lv[sp];
        asum += a;
        v4h op = *(const v4h*)(Opart + (((size_t)sp * H + h) * S + q) * D + d0);
#pragma unroll
        for (int j = 0; j < 4; ++j) o[j] += a * (float)op[j];
    }
    const float inv = 1.f / asum;
    v4h co;
#pragma unroll
    for (int j = 0; j < 4; ++j) co[j] = (f16)(o[j] * inv);
    *(v4h*)(cat + (size_t)q * E + idx) = co;
}

// ---------------------------------------------------------------------------
// Kernel 3: out-proj GEMM (m97 recipe). Residual from Xh (fp16); y out fp16.
// grid (S/64, E/64).
// ---------------------------------------------------------------------------
__global__ __launch_bounds__(256) void gemm_y(
        const f16* __restrict__ cat, const f16* __restrict__ WoB,
        const float* __restrict__ bo, const f16* __restrict__ Xh,
        f16* __restrict__ y) {
    const int m0 = blockIdx.x * 64;
    const int n0 = blockIdx.y * 64;
    const int t = threadIdx.x;
    const int wave = t >> 6, lane = t & 63;
    const int quad = lane >> 4, l16 = lane & 15;
    const int wm = wave >> 1, wn = wave & 1;

    __shared__ f16 As[64 * 64];
    __shared__ f16 Bs[64 * 64];

    v4f acc[2][2] = {};
    const int lrow8 = lane >> 3, lg = lane & 7;

    for (int k0 = 0; k0 < E; k0 += 64) {
        __syncthreads();
#pragma unroll
        for (int jj = 0; jj < 2; ++jj) {
            const int j = wave * 2 + jj;
            const int row = j * 8 + lrow8;
            const int g = lg ^ (row & 7);
            glds16(cat + (size_t)(m0 + row) * E + k0 + g * 8, &As[j * 512]);
            glds16(WoB + (size_t)(n0 + row) * E + k0 + g * 8, &Bs[j * 512]);
        }
        __syncthreads();

#pragma unroll
        for (int ks = 0; ks < 2; ++ks) {
            v8h a[2], b[2];
#pragma unroll
            for (int mt = 0; mt < 2; ++mt) {
                const int row = wm * 32 + mt * 16 + l16;
                a[mt] = *(const v8h*)&As[row * 64 + (((ks * 4 + quad) ^ (row & 7)) * 8)];
            }
#pragma unroll
            for (int nt = 0; nt < 2; ++nt) {
                const int row = wn * 32 + nt * 16 + l16;
                b[nt] = *(const v8h*)&Bs[row * 64 + (((ks * 4 + quad) ^ (row & 7)) * 8)];
            }
#pragma unroll
            for (int mt = 0; mt < 2; ++mt)
#pragma unroll
                for (int nt = 0; nt < 2; ++nt)
                    acc[mt][nt] = __builtin_amdgcn_mfma_f32_16x16x32_f16(a[mt], b[nt], acc[mt][nt], 0, 0, 0);
        }
    }

#pragma unroll
    for (int mt = 0; mt < 2; ++mt)
#pragma unroll
        for (int r = 0; r < 4; ++r) {
            const int m = m0 + wm * 32 + mt * 16 + quad * 4 + r;
#pragma unroll
            for (int nt = 0; nt < 2; ++nt) {
                const int e = n0 + wn * 32 + nt * 16 + l16;
                y[(size_t)m * E + e] =
                    (f16)(acc[mt][nt][r] + bo[e] + (float)Xh[(size_t)m * E + e]);
            }
        }
}

// ---------------------------------------------------------------------------
// Kernel 4: LayerNorm rows of y (fp16) -> fp32 out. grid = S, block = 256.
// ---------------------------------------------------------------------------
__global__ void ln(const f16* __restrict__ y,
                   const float* __restrict__ gamma,
                   const float* __restrict__ beta,
                   float* __restrict__ out) {
    const int s = blockIdx.x;
    const int t = threadIdx.x;
    __shared__ float red[256];

    v4h yh = *(const v4h*)(y + (size_t)s * E + t * 4);
    float yv[4];
#pragma unroll
    for (int i = 0; i < 4; ++i) yv[i] = (float)yh[i];

    red[t] = yv[0] + yv[1] + yv[2] + yv[3];
    __syncthreads();
    for (int w = 128; w > 0; w >>= 1) {
        if (t < w) red[t] += red[t + w];
        __syncthreads();
    }
    const float mu = red[0] * (1.f / E);
    __syncthreads();

    float lv = 0.f;
#pragma unroll
    for (int i = 0; i < 4; ++i) { float dd = yv[i] - mu; lv += dd * dd; }
    red[t] = lv;
    __syncthreads();
    for (int w = 128; w > 0; w >>= 1) {
        if (t < w) red[t] += red[t + w];
        __syncthreads();
    }
    const float rstd = rsqrtf(red[0] * (1.f / E) + 1e-5f);

    v4f o;
#pragma unroll
    for (int i = 0; i < 4; ++i) {
        const int e = t * 4 + i;
        o[i] = (yv[i] - mu) * rstd * gamma[e] + beta[e];
    }
    *(v4f*)(out + (size_t)s * E + t * 4) = o;
}

// ---------------------------------------------------------------------------
extern "C" void kernel_launch(void* const* d_in, const int* in_sizes, int n_in,
                              void* d_out, int out_size, void* d_ws, size_t ws_size,
                              hipStream_t stream) {
    const float* x     = (const float*)d_in[0];
    const float* Wk    = (const float*)d_in[1];
    const float* Wq    = (const float*)d_in[2];
    const float* Wv    = (const float*)d_in[3];
    const float* hWk   = (const float*)d_in[4];
    const float* hbk   = (const float*)d_in[5];
    const float* hWv   = (const float*)d_in[6];
    const float* hbv   = (const float*)d_in[7];
    const float* hWq   = (const float*)d_in[8];
    const float* hbq   = (const float*)d_in[9];
    const float* Wo    = (const float*)d_in[10];
    const float* bo    = (const float*)d_in[11];
    const float* gamma = (const float*)d_in[12];
    const float* beta  = (const float*)d_in[13];
    float* out = (float*)d_out;

    // ws layout (MB), no overlap — ws_size is 256 MiB:
    //   Kh @0(4) | Qh @4(4) | VhT @8(4) | Opart @12(16) | ml @28(1)
    //   WoB @29(2) | Xh @31(4) | Wc @35(6) | cat @41(4) | y @45(4)  = 49 MB
    char* base = (char*)d_ws;
    const size_t MB = 1u << 20;
    f16*   Kh    = (f16*)(base);
    f16*   Qh    = (f16*)(base + 4 * MB);
    f16*   VhT   = (f16*)(base + 8 * MB);
    f16*   Opart = (f16*)(base + 12 * MB);
    float* ml    = (float*)(base + 28 * MB);
    f16*   WoB   = (f16*)(base + 29 * MB);
    f16*   Xh    = (f16*)(base + 31 * MB);
    f16*   Wc    = (f16*)(base + 35 * MB);
    f16*   cat   = (f16*)(base + 41 * MB);
    f16*   y     = (f16*)(base + 45 * MB);

    prep<<<3072 + 768, 256, 0, stream>>>(x, Wo, hWk, hWq, hWv, Wk, Wq, Wv,
                                         Xh, WoB, Wc);
    qkv_gemm<<<dim3(S / 128, 3 * H * D / 64), 256, 0, stream>>>(Xh, Wc, hbk, hbq, hbv,
                                                                Kh, Qh, VhT);
    attn_mfma<<<dim3(S / 64, H, NSPLIT), 256, 0, stream>>>(Qh, Kh, VhT, Opart, ml);
    attn_combine<<<S, 256, 0, stream>>>(Opart, ml, cat);
    gemm_y<<<dim3(S / 64, E / 64), 256, 0, stream>>>(cat, WoB, bo, Xh, y);
    ln<<<S, 256, 0, stream>>>(y, gamma, beta, out);
}

// Round 14
// 166.743 us; speedup vs baseline: 1.0203x; 1.0203x over previous
//
#include <hip/hip_runtime.h>
#include <math.h>

#define S 2048
#define E 1024
#define D 64
#define H 16

using f16 = _Float16;
typedef _Float16 v8h __attribute__((ext_vector_type(8)));  // 8 fp16 (4 VGPRs)
typedef _Float16 v4h __attribute__((ext_vector_type(4)));
typedef float v4f __attribute__((ext_vector_type(4)));

#define QSCALE (0.125f * 1.44269504f)   // 1/sqrt(D) * log2(e), folded into Q

__device__ __forceinline__ float fexp2(float x) { return __builtin_amdgcn_exp2f(x); }

// async global->LDS, 16 B per lane; LDS dest = wave-uniform base + lane*16
__device__ __forceinline__ void glds16(const f16* g, f16* l) {
    __builtin_amdgcn_global_load_lds(
        (const __attribute__((address_space(1))) void*)g,
        (__attribute__((address_space(3))) void*)l, 16, 0, 0);
}

// ---------------------------------------------------------------------------
// Kernel 0: fused prep. blocks [0,3072): x/Wo fp32->fp16 converts.
// blocks [3072, 3840): folded weights Wc[type,h] = hW[type,h] @ W[type].
// ---------------------------------------------------------------------------
__global__ void prep(const float* __restrict__ x, const float* __restrict__ Wo,
                     const float* __restrict__ hWk, const float* __restrict__ hWq,
                     const float* __restrict__ hWv,
                     const float* __restrict__ Wk, const float* __restrict__ Wq,
                     const float* __restrict__ Wv,
                     f16* __restrict__ Xh, f16* __restrict__ WoB,
                     f16* __restrict__ Wc) {
    __shared__ f16 Ah[64][72];
    __shared__ f16 Bt[64][72];
    const int t = threadIdx.x;

    if (blockIdx.x < 3072) {             // converts
        const size_t i = (size_t)blockIdx.x * 256 + t;
        const size_t NX = (size_t)S * E / 4;
        if (i < NX) {
            v4f w = ((const v4f*)x)[i];
            v4h h = {(f16)w[0], (f16)w[1], (f16)w[2], (f16)w[3]};
            ((v4h*)Xh)[i] = h;
        } else {
            const size_t j = i - NX;
            v4f w = ((const v4f*)Wo)[j];
            v4h h = {(f16)w[0], (f16)w[1], (f16)w[2], (f16)w[3]};
            ((v4h*)WoB)[j] = h;
        }
        return;
    }

    const int bb = blockIdx.x - 3072;    // 0..767
    const int th = bb >> 4;              // 0..47
    const int type = th >> 4, h = th & 15;
    const int e0 = (bb & 15) * 64;
    const float* hW = ((type == 0) ? hWk : (type == 1) ? hWq : hWv) + (size_t)h * D * D;
    const float* W  = (type == 0) ? Wk : (type == 1) ? Wq : Wv;

    {
        const int r16 = t >> 4, c4 = (t & 15) * 4;
#pragma unroll
        for (int rep = 0; rep < 4; ++rep) {
            const int row = rep * 16 + r16;
            v4f a = *(const v4f*)&hW[(size_t)row * D + c4];
#pragma unroll
            for (int j = 0; j < 4; ++j) Ah[row][c4 + j] = (f16)a[j];
            v4f w = *(const v4f*)&W[(size_t)row * E + e0 + c4];
#pragma unroll
            for (int j = 0; j < 4; ++j) Bt[c4 + j][row] = (f16)w[j];
        }
    }
    __syncthreads();

    const int wave = t >> 6, lane = t & 63;
    const int quad = lane >> 4, l16 = lane & 15;
    v4f acc[4] = {};
#pragma unroll
    for (int ks = 0; ks < 2; ++ks) {
        v8h af = *(const v8h*)&Ah[wave * 16 + l16][ks * 32 + quad * 8];
#pragma unroll
        for (int nt = 0; nt < 4; ++nt) {
            v8h bf = *(const v8h*)&Bt[nt * 16 + l16][ks * 32 + quad * 8];
            acc[nt] = __builtin_amdgcn_mfma_f32_16x16x32_f16(af, bf, acc[nt], 0, 0, 0);
        }
    }
#pragma unroll
    for (int r = 0; r < 4; ++r) {
        const int e2 = wave * 16 + quad * 4 + r;
#pragma unroll
        for (int nt = 0; nt < 4; ++nt)
            Wc[((size_t)th * D + e2) * E + e0 + nt * 16 + l16] = (f16)acc[nt][r];
    }
}

// ---------------------------------------------------------------------------
// Kernel 1: QKV GEMM (m97 recipe). K written [h][s][d]; Q written [h][s][d]
// PRE-SCALED by QSCALE; V written TRANSPOSED to VhT [h][d][s].
// grid (S/128, 3072/64), block 256.
// ---------------------------------------------------------------------------
__global__ __launch_bounds__(256) void qkv_gemm(
        const f16* __restrict__ Xh, const f16* __restrict__ Wc,
        const float* __restrict__ hbk, const float* __restrict__ hbq,
        const float* __restrict__ hbv,
        f16* __restrict__ Kh, f16* __restrict__ Qh, f16* __restrict__ VhT) {
    const int m0 = blockIdx.x * 128;
    const int n0 = blockIdx.y * 64;
    const int type = n0 >> 10, h = (n0 >> 6) & 15;
    const float* hb = ((type == 0) ? hbk : (type == 1) ? hbq : hbv) + h * D;

    const int t = threadIdx.x;
    const int wave = t >> 6, lane = t & 63;
    const int quad = lane >> 4, l16 = lane & 15;
    const int wm = wave >> 1, wn = wave & 1;

    __shared__ f16 As[128 * 64];
    __shared__ f16 Bs[64 * 64];

    v4f acc[4][2] = {};
    const int lrow8 = lane >> 3, lg = lane & 7;

    for (int k0 = 0; k0 < E; k0 += 64) {
        __syncthreads();
#pragma unroll
        for (int jj = 0; jj < 4; ++jj) {
            const int j = wave * 4 + jj;
            const int row = j * 8 + lrow8;
            const int g = lg ^ (row & 7);
            glds16(Xh + (size_t)(m0 + row) * E + k0 + g * 8, &As[j * 512]);
        }
#pragma unroll
        for (int jj = 0; jj < 2; ++jj) {
            const int j = wave * 2 + jj;
            const int row = j * 8 + lrow8;
            const int g = lg ^ (row & 7);
            glds16(Wc + (size_t)(n0 + row) * E + k0 + g * 8, &Bs[j * 512]);
        }
        __syncthreads();

#pragma unroll
        for (int ks = 0; ks < 2; ++ks) {
            v8h a[4], b[2];
#pragma unroll
            for (int mt = 0; mt < 4; ++mt) {
                const int row = wm * 64 + mt * 16 + l16;
                a[mt] = *(const v8h*)&As[row * 64 + (((ks * 4 + quad) ^ (row & 7)) * 8)];
            }
#pragma unroll
            for (int nt = 0; nt < 2; ++nt) {
                const int row = wn * 32 + nt * 16 + l16;
                b[nt] = *(const v8h*)&Bs[row * 64 + (((ks * 4 + quad) ^ (row & 7)) * 8)];
            }
#pragma unroll
            for (int mt = 0; mt < 4; ++mt)
#pragma unroll
                for (int nt = 0; nt < 2; ++nt)
                    acc[mt][nt] = __builtin_amdgcn_mfma_f32_16x16x32_f16(a[mt], b[nt], acc[mt][nt], 0, 0, 0);
        }
    }

    if (type == 2) {                     // V: write transposed [h][d][s]
#pragma unroll
        for (int mt = 0; mt < 4; ++mt)
#pragma unroll
            for (int nt = 0; nt < 2; ++nt) {
                const int d = wn * 32 + nt * 16 + l16;
                const int s = m0 + wm * 64 + mt * 16 + quad * 4;
                const float b = hb[d];
                v4h vh;
#pragma unroll
                for (int r = 0; r < 4; ++r) vh[r] = (f16)(acc[mt][nt][r] + b);
                *(v4h*)(VhT + ((size_t)h * D + d) * S + s) = vh;
            }
    } else {
        f16* outp = (type == 0) ? Kh : Qh;
        const float osc = (type == 1) ? QSCALE : 1.f;
#pragma unroll
        for (int mt = 0; mt < 4; ++mt)
#pragma unroll
            for (int r = 0; r < 4; ++r) {
                const int s = m0 + wm * 64 + mt * 16 + quad * 4 + r;
#pragma unroll
                for (int nt = 0; nt < 2; ++nt) {
                    const int d = wn * 32 + nt * 16 + l16;
                    outp[((size_t)h * S + s) * D + d] = (f16)((acc[mt][nt][r] + hb[d]) * osc);
                }
            }
    }
}

// ---------------------------------------------------------------------------
// Kernel 2: MFMA flash attention (online softmax, log2-domain scores).
// NSPLIT=2 (r14): grid = 32*16*2 = 1024 blocks <= 1280 resident capacity
// (27.6 KB LDS -> 5 blocks/CU) -> ZERO dispatch tail; r12's measured 34%
// occupancy was the 2048-block tail at NSPLIT=4.
// grid = (S/64, H, 2), block = 256.
// NOTE (r11): per-row max is load-bearing — no fixed shift fits fp16.
// ---------------------------------------------------------------------------
#define NSPLIT 2
#define KSPAN (S / NSPLIT)      // 1024
#define ITERS (KSPAN / 64)      // 16
#define PPAD 72

__global__ __launch_bounds__(256, 4) void attn_mfma(
        const f16* __restrict__ Qh, const f16* __restrict__ Kh,
        const f16* __restrict__ VhT, f16* __restrict__ Opart,
        float* __restrict__ ml) {
    const int h = blockIdx.y;
    const int q0 = blockIdx.x * 64;
    const int sp = blockIdx.z;
    const int t = threadIdx.x;
    const int wave = t >> 6, lane = t & 63;
    const int quad = lane >> 4, l16 = lane & 15;

    __shared__ f16 Kt[64 * 64];          // [key][d], swizzled granules
    __shared__ f16 Vt[80 * 64];          // [d][key] rows 0-63; rows 64-79 = 1.0
    __shared__ union { f16 P[4][16][PPAD]; f16 O[64][PPAD]; } PO;

    {
        v4h one = {(f16)1, (f16)1, (f16)1, (f16)1};
        *(v4h*)&Vt[64 * 64 + t * 4] = one;
    }

    const int qrow = q0 + wave * 16 + l16;
    v8h qf[2];
    {
        const v8h* qp = (const v8h*)(Qh + ((size_t)h * S + qrow) * D);
        qf[0] = qp[quad];
        qf[1] = qp[quad + 4];
    }

    v4f oc[5] = {};                      // [0..3]=O^T d-tiles, [4]=l (ones)
    float m_run = -INFINITY;
    const int kb = sp * KSPAN;
    const int srow = lane >> 3, sg = lane & 7;

    for (int it = 0; it < ITERS; ++it) {
        __syncthreads();                 // prev compute done reading Kt/Vt
#pragma unroll
        for (int half = 0; half < 2; ++half) {
            const int row = wave * 16 + half * 8 + srow;
            const int g = sg ^ (row & 7);
            glds16(Kh + ((size_t)h * S + kb + it * 64 + row) * D + g * 8,
                   &Kt[(wave * 16 + half * 8) * 64]);
            glds16(VhT + ((size_t)h * D + row) * S + kb + it * 64 + g * 8,
                   &Vt[(wave * 16 + half * 8) * 64]);
        }
        __syncthreads();                 // DMA drained

        // scores^T (log2-domain): C[key][q], A = K rows, B = Q frag
        v4f sc[4] = {};
#pragma unroll
        for (int ks = 0; ks < 2; ++ks)
#pragma unroll
            for (int mt = 0; mt < 4; ++mt) {
                const int key = mt * 16 + l16;
                v8h kf = *(const v8h*)&Kt[key * 64 + (((ks * 4 + quad) ^ (key & 7)) * 8)];
                sc[mt] = __builtin_amdgcn_mfma_f32_16x16x32_f16(kf, qf[ks], sc[mt], 0, 0, 0);
            }

        // tree max over 16 in-register scores (depth 4, max3-foldable)
        float a0 = fmaxf(sc[0][0], sc[0][1]), a1 = fmaxf(sc[0][2], sc[0][3]);
        float a2 = fmaxf(sc[1][0], sc[1][1]), a3 = fmaxf(sc[1][2], sc[1][3]);
        float a4 = fmaxf(sc[2][0], sc[2][1]), a5 = fmaxf(sc[2][2], sc[2][3]);
        float a6 = fmaxf(sc[3][0], sc[3][1]), a7 = fmaxf(sc[3][2], sc[3][3]);
        float b0 = fmaxf(a0, a1), b1 = fmaxf(a2, a3);
        float b2 = fmaxf(a4, a5), b3 = fmaxf(a6, a7);
        float v = fmaxf(fmaxf(b0, b1), fmaxf(b2, b3));
        v = fmaxf(v, __shfl_xor(v, 16));
        v = fmaxf(v, __shfl_xor(v, 32));
        const float mnew = fmaxf(m_run, v);
        const float alpha = fexp2(m_run - mnew);   // first iter: exp2(-inf)=0
        m_run = mnew;
#pragma unroll
        for (int i = 0; i < 5; ++i) oc[i] *= alpha;

#pragma unroll
        for (int mt = 0; mt < 4; ++mt) {
            const float p0 = fexp2(sc[mt][0] - mnew);
            const float p1 = fexp2(sc[mt][1] - mnew);
            const float p2 = fexp2(sc[mt][2] - mnew);
            const float p3 = fexp2(sc[mt][3] - mnew);
            auto lo = __builtin_amdgcn_cvt_pkrtz(p0, p1);
            auto hi = __builtin_amdgcn_cvt_pkrtz(p2, p3);
            v4h ph; ph[0] = lo[0]; ph[1] = lo[1]; ph[2] = hi[0]; ph[3] = hi[1];
            *(v4h*)&PO.P[wave][l16][mt * 16 + quad * 4] = ph;   // P^T [q][key]
        }
        // Pt is wave-private: in-wave DS ordering suffices (no barrier).

        // PV: O^T += V^T @ P^T (+ ones tile accumulates l)
#pragma unroll
        for (int ks = 0; ks < 2; ++ks) {
            v8h pf = *(const v8h*)&PO.P[wave][l16][ks * 32 + quad * 8];
#pragma unroll
            for (int mt = 0; mt < 5; ++mt) {
                const int dr = mt * 16 + l16;
                v8h vf = *(const v8h*)&Vt[dr * 64 + (((ks * 4 + quad) ^ (dr & 7)) * 8)];
                oc[mt] = __builtin_amdgcn_mfma_f32_16x16x32_f16(vf, pf, oc[mt], 0, 0, 0);
            }
        }
    }

    // epilogue: l from ones tile; normalize; transpose O^T->O via LDS (union)
    const float l = oc[4][0];
    const float invl = 1.f / l;
    __syncthreads();                     // all waves done with PO.P
#pragma unroll
    for (int mt = 0; mt < 4; ++mt) {
        auto lo = __builtin_amdgcn_cvt_pkrtz(oc[mt][0] * invl, oc[mt][1] * invl);
        auto hi = __builtin_amdgcn_cvt_pkrtz(oc[mt][2] * invl, oc[mt][3] * invl);
        v4h oh; oh[0] = lo[0]; oh[1] = lo[1]; oh[2] = hi[0]; oh[3] = hi[1];
        *(v4h*)&PO.O[wave * 16 + l16][mt * 16 + quad * 4] = oh;
    }
    if (quad == 0) {
        float* mlp = ml + (((size_t)sp * H + h) * S + qrow) * 2;
        mlp[0] = m_run;
        mlp[1] = l;
    }
    __syncthreads();
    {
        const int q = t >> 2, dg = (t & 3) * 16;
        v8h o0 = *(const v8h*)&PO.O[q][dg];
        v8h o1 = *(const v8h*)&PO.O[q][dg + 8];
        f16* dst = Opart + (((size_t)sp * H + h) * S + q0 + q) * D + dg;
        *(v8h*)dst = o0;
        *(v8h*)(dst + 8) = o1;
    }
}

// ---------------------------------------------------------------------------
// Kernel 2b: combine 2 splits (m-aware), vectorized v4h. grid = S, block 256.
// ---------------------------------------------------------------------------
__global__ void attn_combine(const f16* __restrict__ Opart,
                             const float* __restrict__ ml,
                             f16* __restrict__ cat) {
    const int q = blockIdx.x;
    const int t = threadIdx.x;
    const int idx = t * 4;                // 0..1020
    const int h = idx >> 6, d0 = idx & 63;

    float m[NSPLIT], lv[NSPLIT];
    float M = -INFINITY;
#pragma unroll
    for (int sp = 0; sp < NSPLIT; ++sp) {
        const float* mlp = ml + (((size_t)sp * H + h) * S + q) * 2;
        m[sp] = mlp[0]; lv[sp] = mlp[1];
        M = fmaxf(M, m[sp]);
    }
    float asum = 0.f;
    float o[4] = {0.f, 0.f, 0.f, 0.f};
#pragma unroll
    for (int sp = 0; sp < NSPLIT; ++sp) {
        const float a = fexp2(m[sp] - M) * lv[sp];
        asum += a;
        v4h op = *(const v4h*)(Opart + (((size_t)sp * H + h) * S + q) * D + d0);
#pragma unroll
        for (int j = 0; j < 4; ++j) o[j] += a * (float)op[j];
    }
    const float inv = 1.f / asum;
    v4h co;
#pragma unroll
    for (int j = 0; j < 4; ++j) co[j] = (f16)(o[j] * inv);
    *(v4h*)(cat + (size_t)q * E + idx) = co;
}

// ---------------------------------------------------------------------------
// Kernel 3: out-proj GEMM (m97 recipe). Residual from Xh (fp16); y out fp16.
// grid (S/64, E/64).
// ---------------------------------------------------------------------------
__global__ __launch_bounds__(256) void gemm_y(
        const f16* __restrict__ cat, const f16* __restrict__ WoB,
        const float* __restrict__ bo, const f16* __restrict__ Xh,
        f16* __restrict__ y) {
    const int m0 = blockIdx.x * 64;
    const int n0 = blockIdx.y * 64;
    const int t = threadIdx.x;
    const int wave = t >> 6, lane = t & 63;
    const int quad = lane >> 4, l16 = lane & 15;
    const int wm = wave >> 1, wn = wave & 1;

    __shared__ f16 As[64 * 64];
    __shared__ f16 Bs[64 * 64];

    v4f acc[2][2] = {};
    const int lrow8 = lane >> 3, lg = lane & 7;

    for (int k0 = 0; k0 < E; k0 += 64) {
        __syncthreads();
#pragma unroll
        for (int jj = 0; jj < 2; ++jj) {
            const int j = wave * 2 + jj;
            const int row = j * 8 + lrow8;
            const int g = lg ^ (row & 7);
            glds16(cat + (size_t)(m0 + row) * E + k0 + g * 8, &As[j * 512]);
            glds16(WoB + (size_t)(n0 + row) * E + k0 + g * 8, &Bs[j * 512]);
        }
        __syncthreads();

#pragma unroll
        for (int ks = 0; ks < 2; ++ks) {
            v8h a[2], b[2];
#pragma unroll
            for (int mt = 0; mt < 2; ++mt) {
                const int row = wm * 32 + mt * 16 + l16;
                a[mt] = *(const v8h*)&As[row * 64 + (((ks * 4 + quad) ^ (row & 7)) * 8)];
            }
#pragma unroll
            for (int nt = 0; nt < 2; ++nt) {
                const int row = wn * 32 + nt * 16 + l16;
                b[nt] = *(const v8h*)&Bs[row * 64 + (((ks * 4 + quad) ^ (row & 7)) * 8)];
            }
#pragma unroll
            for (int mt = 0; mt < 2; ++mt)
#pragma unroll
                for (int nt = 0; nt < 2; ++nt)
                    acc[mt][nt] = __builtin_amdgcn_mfma_f32_16x16x32_f16(a[mt], b[nt], acc[mt][nt], 0, 0, 0);
        }
    }

#pragma unroll
    for (int mt = 0; mt < 2; ++mt)
#pragma unroll
        for (int r = 0; r < 4; ++r) {
            const int m = m0 + wm * 32 + mt * 16 + quad * 4 + r;
#pragma unroll
            for (int nt = 0; nt < 2; ++nt) {
                const int e = n0 + wn * 32 + nt * 16 + l16;
                y[(size_t)m * E + e] =
                    (f16)(acc[mt][nt][r] + bo[e] + (float)Xh[(size_t)m * E + e]);
            }
        }
}

// ---------------------------------------------------------------------------
// Kernel 4: LayerNorm rows of y (fp16) -> fp32 out. grid = S, block = 256.
// ---------------------------------------------------------------------------
__global__ void ln(const f16* __restrict__ y,
                   const float* __restrict__ gamma,
                   const float* __restrict__ beta,
                   float* __restrict__ out) {
    const int s = blockIdx.x;
    const int t = threadIdx.x;
    __shared__ float red[256];

    v4h yh = *(const v4h*)(y + (size_t)s * E + t * 4);
    float yv[4];
#pragma unroll
    for (int i = 0; i < 4; ++i) yv[i] = (float)yh[i];

    red[t] = yv[0] + yv[1] + yv[2] + yv[3];
    __syncthreads();
    for (int w = 128; w > 0; w >>= 1) {
        if (t < w) red[t] += red[t + w];
        __syncthreads();
    }
    const float mu = red[0] * (1.f / E);
    __syncthreads();

    float lv = 0.f;
#pragma unroll
    for (int i = 0; i < 4; ++i) { float dd = yv[i] - mu; lv += dd * dd; }
    red[t] = lv;
    __syncthreads();
    for (int w = 128; w > 0; w >>= 1) {
        if (t < w) red[t] += red[t + w];
        __syncthreads();
    }
    const float rstd = rsqrtf(red[0] * (1.f / E) + 1e-5f);

    v4f o;
#pragma unroll
    for (int i = 0; i < 4; ++i) {
        const int e = t * 4 + i;
        o[i] = (yv[i] - mu) * rstd * gamma[e] + beta[e];
    }
    *(v4f*)(out + (size_t)s * E + t * 4) = o;
}

// ---------------------------------------------------------------------------
extern "C" void kernel_launch(void* const* d_in, const int* in_sizes, int n_in,
                              void* d_out, int out_size, void* d_ws, size_t ws_size,
                              hipStream_t stream) {
    const float* x     = (const float*)d_in[0];
    const float* Wk    = (const float*)d_in[1];
    const float* Wq    = (const float*)d_in[2];
    const float* Wv    = (const float*)d_in[3];
    const float* hWk   = (const float*)d_in[4];
    const float* hbk   = (const float*)d_in[5];
    const float* hWv   = (const float*)d_in[6];
    const float* hbv   = (const float*)d_in[7];
    const float* hWq   = (const float*)d_in[8];
    const float* hbq   = (const float*)d_in[9];
    const float* Wo    = (const float*)d_in[10];
    const float* bo    = (const float*)d_in[11];
    const float* gamma = (const float*)d_in[12];
    const float* beta  = (const float*)d_in[13];
    float* out = (float*)d_out;

    // ws layout (MB), no overlap — ws_size is 256 MiB:
    //   Kh @0(4) | Qh @4(4) | VhT @8(4) | Opart @12(8) | ml @20(0.5)
    //   WoB @21(2) | Xh @23(4) | Wc @27(6) | cat @33(4) | y @37(4)  = 41 MB
    char* base = (char*)d_ws;
    const size_t MB = 1u << 20;
    f16*   Kh    = (f16*)(base);
    f16*   Qh    = (f16*)(base + 4 * MB);
    f16*   VhT   = (f16*)(base + 8 * MB);
    f16*   Opart = (f16*)(base + 12 * MB);
    float* ml    = (float*)(base + 20 * MB);
    f16*   WoB   = (f16*)(base + 21 * MB);
    f16*   Xh    = (f16*)(base + 23 * MB);
    f16*   Wc    = (f16*)(base + 27 * MB);
    f16*   cat   = (f16*)(base + 33 * MB);
    f16*   y     = (f16*)(base + 37 * MB);

    prep<<<3072 + 768, 256, 0, stream>>>(x, Wo, hWk, hWq, hWv, Wk, Wq, Wv,
                                         Xh, WoB, Wc);
    qkv_gemm<<<dim3(S / 128, 3 * H * D / 64), 256, 0, stream>>>(Xh, Wc, hbk, hbq, hbv,
                                                                Kh, Qh, VhT);
    attn_mfma<<<dim3(S / 64, H, NSPLIT), 256, 0, stream>>>(Qh, Kh, VhT, Opart, ml);
    attn_combine<<<S, 256, 0, stream>>>(Opart, ml, cat);
    gemm_y<<<dim3(S / 64, E / 64), 256, 0, stream>>>(cat, WoB, bo, Xh, y);
    ln<<<S, 256, 0, stream>>>(y, gamma, beta, out);
}